// Round 1
// baseline (279.501 us; speedup 1.0000x reference)
//
#include <hip/hip_runtime.h>
#include <hip/hip_bf16.h>
#include <stdint.h>

#define B_ 8
#define T_ 2048
#define E_ 1024
#define H_ 128
#define BT_ (B_*T_)

typedef unsigned short u16;
typedef __attribute__((ext_vector_type(4))) unsigned short u16x4;
typedef __attribute__((ext_vector_type(8))) short short8;
typedef __attribute__((ext_vector_type(4))) float f32x4;

#define MFMA_BF16(a,b,c) __builtin_amdgcn_mfma_f32_16x16x32_bf16((a),(b),(c),0,0,0)

__device__ __forceinline__ u16 bf16u(float f) {
  union { float f; unsigned u; } v; v.f = f;
  unsigned r = v.u + 0x7FFFu + ((v.u >> 16) & 1u);
  return (u16)(r >> 16);
}

// async global->LDS, 16B per lane; lds dest must be wave-uniform base.
__device__ __forceinline__ void gl16(const void* g, void* l) {
  __builtin_amdgcn_global_load_lds(
      (const __attribute__((address_space(1))) void*)g,
      (__attribute__((address_space(3))) void*)l, 16, 0, 0);
}

// Stage an R-row tile, CB bytes per row, into LDS laid out row-major [R][CB].
// gstride = global row stride in bytes. 4 waves assumed (256 threads).
template<int R, int CB>
__device__ __forceinline__ void stage_tile(const char* g, int gstride, char* lds) {
  const int lane = threadIdx.x & 63;
  const int wid  = threadIdx.x >> 6;
  constexpr int RPC   = 1024 / CB;          // rows per 1KB wave-call
  constexpr int CALLS = (R * CB) / 1024;    // total wave-calls
  constexpr int CPW   = CALLS / 4;          // calls per wave
  constexpr int LPR   = CB / 16;            // lanes per row
#pragma unroll
  for (int c = 0; c < CPW; ++c) {
    const int call = wid * CPW + c;
    const int r0   = call * RPC;            // wave-uniform
    const int row  = r0 + lane / LPR;
    const int colb = (lane % LPR) * 16;
    gl16(g + (size_t)row * gstride + colb, lds + (size_t)r0 * CB);
  }
}

// ---------------- kernel 0a: X fp32 -> bf16 ----------------
__global__ void k_convert_x(const float* __restrict__ X, u16* __restrict__ Xb) {
  const int n4 = BT_ * E_ / 4;
  for (int i = blockIdx.x * 256 + threadIdx.x; i < n4; i += gridDim.x * 256) {
    float4 v = ((const float4*)X)[i];
    u16x4 o;
    o.x = bf16u(v.x); o.y = bf16u(v.y); o.z = bf16u(v.z); o.w = bf16u(v.w);
    ((u16x4*)Xb)[i] = o;
  }
}

// ---------------- kernel 0b: Wt[384][1024] = [Wq/32 | Wk | Wv]^T ----------------
__global__ void k_build_wt(const float* __restrict__ Wq, const float* __restrict__ Wk,
                           const float* __restrict__ Wv, u16* __restrict__ Wt) {
  int idx = blockIdx.x * 256 + threadIdx.x;
  if (idx >= 384 * 1024) return;
  int r = idx >> 10;        // output row 0..383
  int e = idx & 1023;       // col 0..1023
  int i = r >> 7;           // 0:q 1:k 2:v
  int h = r & 127;
  const float* W = (i == 0) ? Wq : (i == 1) ? Wk : Wv;
  float v = W[(size_t)e * 128 + h];
  if (i == 0) v *= 0.03125f;   // fold 1/sqrt(E) = 1/32 into Q
  Wt[idx] = bf16u(v);
}

// ---------------- kernel 1: QKV GEMM (Bt input), 128x128 tile, BK=64 ----------------
__global__ __launch_bounds__(256) void k_qkv_gemm(const u16* __restrict__ Xb, const u16* __restrict__ Wt,
                                                  u16* __restrict__ Qs, u16* __restrict__ Kb,
                                                  u16* __restrict__ Vt) {
  __shared__ __align__(16) u16 As[128 * 64];
  __shared__ __align__(16) u16 Bs[128 * 64];
  const int m0   = blockIdx.x * 128;
  const int nsel = blockIdx.y;          // 0->Q 1->K 2->V
  const int n0   = nsel * 128;
  const int lane = threadIdx.x & 63;
  const int wid  = threadIdx.x >> 6;
  const int ln = lane & 15, hi = lane >> 4;
  const int wm = (wid >> 1) * 64, wn = (wid & 1) * 64;
  f32x4 acc[4][4] = {};
  for (int ks = 0; ks < E_; ks += 64) {
    stage_tile<128, 128>((const char*)(Xb + (size_t)m0 * E_ + ks), E_ * 2, (char*)As);
    stage_tile<128, 128>((const char*)(Wt + (size_t)n0 * E_ + ks), E_ * 2, (char*)Bs);
    __syncthreads();
#pragma unroll
    for (int kk = 0; kk < 2; ++kk) {
      short8 a[4], b[4];
#pragma unroll
      for (int mf = 0; mf < 4; ++mf)
        a[mf] = *(const short8*)&As[(wm + mf * 16 + ln) * 64 + kk * 32 + hi * 8];
#pragma unroll
      for (int nf = 0; nf < 4; ++nf)
        b[nf] = *(const short8*)&Bs[(wn + nf * 16 + ln) * 64 + kk * 32 + hi * 8];
#pragma unroll
      for (int mf = 0; mf < 4; ++mf)
#pragma unroll
        for (int nf = 0; nf < 4; ++nf)
          acc[mf][nf] = MFMA_BF16(a[mf], b[nf], acc[mf][nf]);
    }
    __syncthreads();
  }
#pragma unroll
  for (int mf = 0; mf < 4; ++mf)
#pragma unroll
    for (int nf = 0; nf < 4; ++nf)
#pragma unroll
      for (int i = 0; i < 4; ++i) {
        int r = m0 + wm + mf * 16 + hi * 4 + i;
        int c = wn + nf * 16 + ln;
        u16 u = bf16u(acc[mf][nf][i]);
        if (nsel == 0)      Qs[(size_t)r * H_ + c] = u;
        else if (nsel == 1) Kb[(size_t)r * H_ + c] = u;
        else {
          int bb = r >> 11, t = r & (T_ - 1);
          Vt[((size_t)bb * H_ + c) * T_ + t] = u;   // V transposed per batch
        }
      }
}

// ---------------- kernel 2: column sums of exp(S) under causal mask ----------------
// grid (qc=4, kt=16, b=8); each wg: k-tile of 128 cols, q-chunk of up to 8 q64-tiles.
__global__ __launch_bounds__(256) void k_col_stats(const u16* __restrict__ Qs, const u16* __restrict__ Kb,
                                                   float* __restrict__ colsum) {
  __shared__ __align__(16) u16 Ks[128 * 128];
  __shared__ __align__(16) u16 Qt[64 * 128];
  __shared__ float cs[128];
  const int qc = blockIdx.x, kt = blockIdx.y, b = blockIdx.z;
  const int k0 = kt * 128;
  int qlo = qc * 8;  if (2 * kt > qlo) qlo = 2 * kt;
  int qhi = qc * 8 + 8;  if (qhi > 32) qhi = 32;
  if (qlo >= qhi) return;
  const int lane = threadIdx.x & 63, wid = threadIdx.x >> 6;
  const int ln = lane & 15, hi = lane >> 4;
  const int wm = wid * 16;
  stage_tile<128, 256>((const char*)(Kb + ((size_t)b * T_ + k0) * H_), H_ * 2, (char*)Ks);
  if (threadIdx.x < 128) cs[threadIdx.x] = 0.f;
  __syncthreads();
  for (int qi = qlo; qi < qhi; ++qi) {
    const int q0 = qi * 64;
    stage_tile<64, 256>((const char*)(Qs + ((size_t)b * T_ + q0) * H_), H_ * 2, (char*)Qt);
    __syncthreads();
    f32x4 acc[8] = {};
#pragma unroll
    for (int kk = 0; kk < 4; ++kk) {
      short8 a = *(const short8*)&Qt[(wm + ln) * 128 + kk * 32 + hi * 8];
#pragma unroll
      for (int nf = 0; nf < 8; ++nf) {
        short8 bb = *(const short8*)&Ks[(nf * 16 + ln) * 128 + kk * 32 + hi * 8];
        acc[nf] = MFMA_BF16(a, bb, acc[nf]);
      }
    }
#pragma unroll
    for (int nf = 0; nf < 8; ++nf) {
      float s = 0.f;
      int k = k0 + nf * 16 + ln;
#pragma unroll
      for (int i = 0; i < 4; ++i) {
        int q = q0 + wm + hi * 4 + i;
        s += (q >= k) ? __expf(acc[nf][i]) : 0.f;
      }
      s += __shfl_xor(s, 16);
      s += __shfl_xor(s, 32);
      if (hi == 0) atomicAdd(&cs[nf * 16 + ln], s);
    }
    __syncthreads();
  }
  if (threadIdx.x < 128)
    atomicAdd(&colsum[(size_t)b * T_ + k0 + threadIdx.x], cs[threadIdx.x]);
}

// ---------------- kernel 2b: invl = 1/colsum ----------------
__global__ void k_make_invl(const float* __restrict__ colsum, float* __restrict__ invl) {
  int i = blockIdx.x * 256 + threadIdx.x;
  if (i < BT_) invl[i] = 1.f / colsum[i];
}

// ---------------- kernel 3: O = (exp(S) * invl) @ V, causal ----------------
// grid (qt=32, b=8), QBLK=64, KBLK=64, 4 waves each own 16 q-rows.
__global__ __launch_bounds__(256) void k_attn_out(const u16* __restrict__ Qs, const u16* __restrict__ Kb,
                                                  const u16* __restrict__ Vt, const float* __restrict__ invl,
                                                  float* __restrict__ out) {
  __shared__ __align__(16) u16 Qt[64 * 128];   // 16KB
  __shared__ __align__(16) u16 Ks[64 * 128];   // 16KB
  __shared__ __align__(16) u16 Vs[128 * 64];   // [h][k] 16KB
  __shared__ __align__(16) u16 Ps[64 * 64];    // 8KB
  const int qt = blockIdx.x, b = blockIdx.y;
  const int q0 = qt * 64;
  const int lane = threadIdx.x & 63, wid = threadIdx.x >> 6;
  const int ln = lane & 15, hi = lane >> 4;
  const int wm = wid * 16;
  stage_tile<64, 256>((const char*)(Qs + ((size_t)b * T_ + q0) * H_), H_ * 2, (char*)Qt);
  f32x4 oacc[8] = {};
  for (int kt = 0; kt <= qt; ++kt) {
    const int k0 = kt * 64;
    stage_tile<64, 256>((const char*)(Kb + ((size_t)b * T_ + k0) * H_), H_ * 2, (char*)Ks);
    stage_tile<128, 128>((const char*)(Vt + (size_t)b * H_ * T_ + k0), T_ * 2, (char*)Vs);
    __syncthreads();
    // S tile: wave rows wm..wm+15 x 64 keys
    f32x4 acc[4] = {};
#pragma unroll
    for (int kk = 0; kk < 4; ++kk) {
      short8 a = *(const short8*)&Qt[(wm + ln) * 128 + kk * 32 + hi * 8];
#pragma unroll
      for (int nf = 0; nf < 4; ++nf) {
        short8 bb = *(const short8*)&Ks[(nf * 16 + ln) * 128 + kk * 32 + hi * 8];
        acc[nf] = MFMA_BF16(a, bb, acc[nf]);
      }
    }
#pragma unroll
    for (int nf = 0; nf < 4; ++nf) {
      int k = k0 + nf * 16 + ln;
      float il = invl[(size_t)b * T_ + k];
#pragma unroll
      for (int i = 0; i < 4; ++i) {
        int q = q0 + wm + hi * 4 + i;
        float w = (k <= q) ? __expf(acc[nf][i]) * il : 0.f;
        Ps[(wm + hi * 4 + i) * 64 + nf * 16 + ln] = bf16u(w);
      }
    }
    __syncthreads();
    // O += P @ V  (A = Ps [q][k], Bt = Vs [h][k])
#pragma unroll
    for (int kk = 0; kk < 2; ++kk) {
      short8 a = *(const short8*)&Ps[(wm + ln) * 64 + kk * 32 + hi * 8];
#pragma unroll
      for (int nf = 0; nf < 8; ++nf) {
        short8 bb = *(const short8*)&Vs[(nf * 16 + ln) * 64 + kk * 32 + hi * 8];
        oacc[nf] = MFMA_BF16(a, bb, oacc[nf]);
      }
    }
    __syncthreads();
  }
#pragma unroll
  for (int nf = 0; nf < 8; ++nf)
#pragma unroll
    for (int i = 0; i < 4; ++i) {
      int q = q0 + wm + hi * 4 + i;
      out[((size_t)b * T_ + q) * H_ + nf * 16 + ln] = oacc[nf][i];
    }
}

extern "C" void kernel_launch(void* const* d_in, const int* in_sizes, int n_in,
                              void* d_out, int out_size, void* d_ws, size_t ws_size,
                              hipStream_t stream) {
  const float* X  = (const float*)d_in[0];
  const float* Wq = (const float*)d_in[1];
  const float* Wk = (const float*)d_in[2];
  const float* Wv = (const float*)d_in[3];
  float* out = (float*)d_out;
  char* ws = (char*)d_ws;

  u16*  Xb     = (u16*)(ws + 0);              // 33554432 B
  u16*  Wt     = (u16*)(ws + 33554432);       //   786432 B
  u16*  Qs     = (u16*)(ws + 34340864);       //  4194304 B
  u16*  Kb     = (u16*)(ws + 38535168);       //  4194304 B
  u16*  Vt     = (u16*)(ws + 42729472);       //  4194304 B
  float* colsum = (float*)(ws + 46923776);    //    65536 B
  float* invl   = (float*)(ws + 46989312);    //    65536 B

  hipMemsetAsync(colsum, 0, BT_ * sizeof(float), stream);
  k_convert_x<<<2048, 256, 0, stream>>>(X, Xb);
  k_build_wt<<<1536, 256, 0, stream>>>(Wq, Wk, Wv, Wt);
  k_qkv_gemm<<<dim3(128, 3), 256, 0, stream>>>(Xb, Wt, Qs, Kb, Vt);
  k_col_stats<<<dim3(4, 16, 8), 256, 0, stream>>>(Qs, Kb, colsum);
  k_make_invl<<<64, 256, 0, stream>>>(colsum, invl);
  k_attn_out<<<dim3(32, 8), 256, 0, stream>>>(Qs, Kb, Vt, invl, out);
}

// Round 2
// 206.240 us; speedup vs baseline: 1.3552x; 1.3552x over previous
//
#include <hip/hip_runtime.h>
#include <hip/hip_bf16.h>
#include <stdint.h>

#define B_ 8
#define T_ 2048
#define E_ 1024
#define H_ 128
#define BT_ (B_*T_)

typedef unsigned short u16;
typedef unsigned int u32;
typedef __attribute__((ext_vector_type(4))) unsigned short u16x4;
typedef __attribute__((ext_vector_type(8))) short short8;
typedef __attribute__((ext_vector_type(4))) float f32x4;

#define MFMA_BF16(a,b,c) __builtin_amdgcn_mfma_f32_16x16x32_bf16((a),(b),(c),0,0,0)

__device__ __forceinline__ u16 bf16u(float f) {
  union { float f; unsigned u; } v; v.f = f;
  unsigned r = v.u + 0x7FFFu + ((v.u >> 16) & 1u);
  return (u16)(r >> 16);
}
__device__ __forceinline__ float ubf16(u16 u) {
  union { unsigned u; float f; } v; v.u = ((unsigned)u) << 16; return v.f;
}

// async global->LDS, 16B per lane; lds dest must be wave-uniform base.
__device__ __forceinline__ void gl16(const void* g, void* l) {
  __builtin_amdgcn_global_load_lds(
      (const __attribute__((address_space(1))) void*)g,
      (__attribute__((address_space(3))) void*)l, 16, 0, 0);
}

// Stage an R-row tile, CB bytes per row, into LDS laid out row-major [R][CB].
// SWZ: apply XOR-swizzle via pre-swizzled GLOBAL source (LDS dest stays linear).
// Readers must XOR their 16B-slot index with (row&7). 4 waves assumed.
template<int R, int CB, bool SWZ>
__device__ __forceinline__ void stage_tile(const char* g, int gstride, char* lds) {
  const int lane = threadIdx.x & 63;
  const int wid  = threadIdx.x >> 6;
  constexpr int LPR   = CB / 16;            // lanes per row
  constexpr int RPC   = 1024 / CB;          // rows per 1KB wave-call
  constexpr int CALLS = (R * CB) / 1024;    // total wave-calls
  constexpr int CPW   = CALLS / 4;          // calls per wave
#pragma unroll
  for (int c = 0; c < CPW; ++c) {
    const int call = wid * CPW + c;
    const int r0   = call * RPC;            // wave-uniform
    const int row  = r0 + lane / LPR;
    int s = lane % LPR;
    if (SWZ) s = s ^ (row & 7);
    gl16(g + (size_t)row * gstride + s * 16, lds + (size_t)r0 * CB);
  }
}

// Read a bf16x8 fragment from a SWZ-staged tile. colu16 must be a multiple of 8.
__device__ __forceinline__ short8 fragr(const u16* lds, int row, int colu16, int CBu) {
  const int slot = (colu16 >> 3) ^ (row & 7);
  return *(const short8*)&lds[(size_t)row * CBu + (slot << 3)];
}

// ---------------- kernel 0a: X fp32 -> bf16 ----------------
__global__ void k_convert_x(const float* __restrict__ X, u16* __restrict__ Xb) {
  const int n4 = BT_ * E_ / 4;
  for (int i = blockIdx.x * 256 + threadIdx.x; i < n4; i += gridDim.x * 256) {
    float4 v = ((const float4*)X)[i];
    u16x4 o;
    o.x = bf16u(v.x); o.y = bf16u(v.y); o.z = bf16u(v.z); o.w = bf16u(v.w);
    ((u16x4*)Xb)[i] = o;
  }
}

// ---------------- kernel 0b: Wt[384][1024] = [Wq/32 | Wk | Wv]^T ----------------
__global__ void k_build_wt(const float* __restrict__ Wq, const float* __restrict__ Wk,
                           const float* __restrict__ Wv, u16* __restrict__ Wt) {
  int idx = blockIdx.x * 256 + threadIdx.x;
  if (idx >= 384 * 1024) return;
  int r = idx >> 10;        // output row 0..383
  int e = idx & 1023;       // col 0..1023
  int i = r >> 7;           // 0:q 1:k 2:v
  int h = r & 127;
  const float* W = (i == 0) ? Wq : (i == 1) ? Wk : Wv;
  float v = W[(size_t)e * 128 + h];
  if (i == 0) v *= 0.03125f;   // fold 1/sqrt(E) = 1/32 into Q
  Wt[idx] = bf16u(v);
}

// ---------------- kernel 1: QKV GEMM (Bt input), 128x128 tile, BK=64, swizzled LDS ----
__global__ __launch_bounds__(256) void k_qkv_gemm(const u16* __restrict__ Xb, const u16* __restrict__ Wt,
                                                  u16* __restrict__ Qs, u16* __restrict__ Kb,
                                                  u16* __restrict__ Vt) {
  __shared__ __align__(16) u16 As[128 * 64];
  __shared__ __align__(16) u16 Bs[128 * 64];
  const int m0   = blockIdx.x * 128;
  const int nsel = blockIdx.y;          // 0->Q 1->K 2->V
  const int n0   = nsel * 128;
  const int lane = threadIdx.x & 63;
  const int wid  = threadIdx.x >> 6;
  const int ln = lane & 15, hi = lane >> 4;
  const int wm = (wid >> 1) * 64, wn = (wid & 1) * 64;
  f32x4 acc[4][4] = {};
  for (int ks = 0; ks < E_; ks += 64) {
    stage_tile<128, 128, true>((const char*)(Xb + (size_t)m0 * E_ + ks), E_ * 2, (char*)As);
    stage_tile<128, 128, true>((const char*)(Wt + (size_t)n0 * E_ + ks), E_ * 2, (char*)Bs);
    __syncthreads();
#pragma unroll
    for (int kk = 0; kk < 2; ++kk) {
      short8 a[4], b[4];
#pragma unroll
      for (int mf = 0; mf < 4; ++mf)
        a[mf] = fragr(As, wm + mf * 16 + ln, kk * 32 + hi * 8, 64);
#pragma unroll
      for (int nf = 0; nf < 4; ++nf)
        b[nf] = fragr(Bs, wn + nf * 16 + ln, kk * 32 + hi * 8, 64);
#pragma unroll
      for (int mf = 0; mf < 4; ++mf)
#pragma unroll
        for (int nf = 0; nf < 4; ++nf)
          acc[mf][nf] = MFMA_BF16(a[mf], b[nf], acc[mf][nf]);
    }
    __syncthreads();
  }
#pragma unroll
  for (int mf = 0; mf < 4; ++mf)
#pragma unroll
    for (int nf = 0; nf < 4; ++nf)
#pragma unroll
      for (int i = 0; i < 4; ++i) {
        int r = m0 + wm + mf * 16 + hi * 4 + i;
        int c = wn + nf * 16 + ln;
        u16 u = bf16u(acc[mf][nf][i]);
        if (nsel == 0)      Qs[(size_t)r * H_ + c] = u;
        else if (nsel == 1) Kb[(size_t)r * H_ + c] = u;
        else {
          int bb = r >> 11, t = r & (T_ - 1);
          Vt[((size_t)bb * H_ + c) * T_ + t] = u;   // V transposed per batch
        }
      }
}

// ---------------- kernel 2: score pass ----------------
// One wg per causal 128x128 tile. Computes S = Q K^T (scale folded), exp+mask,
// column-sum atomics into colsum, writes Pexp bf16 into packed tile buffer.
__global__ __launch_bounds__(256) void k_score(const u16* __restrict__ Qs, const u16* __restrict__ Kb,
                                               u16* __restrict__ P, float* __restrict__ colsum,
                                               int b_base) {
  __shared__ __align__(16) u16 QtPs[128 * 128];   // Qt during MFMA, then Ps
  __shared__ __align__(16) u16 Ks[128 * 128];
  __shared__ float cs[128];
  const int tid = blockIdx.x;
  const int bl  = blockIdx.y;
  const int b   = b_base + bl;
  // decode triangular tile id -> (qt, kt), qt >= kt
  int qt = (int)((sqrtf(8.f * tid + 1.f) - 1.f) * 0.5f);
  while ((qt + 1) * (qt + 2) / 2 <= tid) ++qt;
  while (qt * (qt + 1) / 2 > tid) --qt;
  const int kt = tid - qt * (qt + 1) / 2;

  const int lane = threadIdx.x & 63, wid = threadIdx.x >> 6;
  const int ln = lane & 15, hi = lane >> 4;
  const int wq0 = wid * 32;

  stage_tile<128, 256, true>((const char*)(Qs + ((size_t)b * T_ + qt * 128) * H_), H_ * 2, (char*)QtPs);
  stage_tile<128, 256, true>((const char*)(Kb + ((size_t)b * T_ + kt * 128) * H_), H_ * 2, (char*)Ks);
  if (threadIdx.x < 128) cs[threadIdx.x] = 0.f;
  __syncthreads();

  f32x4 acc[2][8] = {};
#pragma unroll
  for (int kk = 0; kk < 4; ++kk) {
    short8 a[2], bf[8];
#pragma unroll
    for (int mf = 0; mf < 2; ++mf)
      a[mf] = fragr(QtPs, wq0 + mf * 16 + ln, kk * 32 + hi * 8, 128);
#pragma unroll
    for (int nf = 0; nf < 8; ++nf)
      bf[nf] = fragr(Ks, nf * 16 + ln, kk * 32 + hi * 8, 128);
#pragma unroll
    for (int mf = 0; mf < 2; ++mf)
#pragma unroll
      for (int nf = 0; nf < 8; ++nf)
        acc[mf][nf] = MFMA_BF16(a[mf], bf[nf], acc[mf][nf]);
  }

  // exp + mask (diag tiles only) + column partial sums
  const bool diag = (qt == kt);
#pragma unroll
  for (int nf = 0; nf < 8; ++nf) {
    float s = 0.f;
    const int k = nf * 16 + ln;   // local k
#pragma unroll
    for (int mf = 0; mf < 2; ++mf) {
#pragma unroll
      for (int i = 0; i < 4; ++i) {
        const int q = wq0 + mf * 16 + hi * 4 + i;  // local q
        float w = __expf(acc[mf][nf][i]);
        if (diag && q < k) w = 0.f;
        acc[mf][nf][i] = w;
        s += w;
      }
    }
    s += __shfl_xor(s, 16);
    s += __shfl_xor(s, 32);
    if (hi == 0) atomicAdd(&cs[nf * 16 + ln], s);
  }
  __syncthreads();   // Qt reads done, cs complete

  // write P tile (bf16) into QtPs with XOR-swizzle, paired b32 writes
  u16* Ps = QtPs;
  const bool evenlane = !(ln & 1);
#pragma unroll
  for (int mf = 0; mf < 2; ++mf)
#pragma unroll
    for (int nf = 0; nf < 8; ++nf) {
      f32x4 v = acc[mf][nf];
      f32x4 pv;
#pragma unroll
      for (int i = 0; i < 4; ++i) pv[i] = __shfl_xor(v[i], 1);
#pragma unroll
      for (int j = 0; j < 2; ++j) {
        const int i = evenlane ? j : (2 + j);
        const float lo = evenlane ? v[i] : pv[i];
        const float hh = evenlane ? pv[i] : v[i];
        const u32 pk = (u32)bf16u(lo) | ((u32)bf16u(hh) << 16);
        const int row = wq0 + mf * 16 + hi * 4 + i;
        const int kc  = nf * 16 + (ln & ~1);
        const int byt = row * 256 + ((((kc >> 3) ^ (row & 7)) << 4) | ((kc & 7) << 1));
        *(u32*)((char*)Ps + byt) = pk;
      }
    }
  __syncthreads();

  // copy Ps -> global packed tile (linear layout), and colsum atomics
  u16* ptile = P + (((size_t)bl * 136 + tid) << 14);   // 16384 u16 per tile
#pragma unroll
  for (int pass = 0; pass < 8; ++pass) {
    const int row = pass * 16 + (threadIdx.x >> 4);
    const int s   = threadIdx.x & 15;
    short8 val = *(const short8*)&Ps[row * 128 + (((s ^ (row & 7)) << 3))];
    *(short8*)&ptile[row * 128 + s * 8] = val;
  }
  if (threadIdx.x < 128)
    atomicAdd(&colsum[(size_t)b * T_ + kt * 128 + threadIdx.x], cs[threadIdx.x]);
}

// ---------------- kernel 3: V' = V * (1/colsum), in place on Vt ----------------
__global__ void k_finalize_v(const float* __restrict__ colsum, u16* __restrict__ Vt, int b_base) {
  const int i8 = blockIdx.x * 256 + threadIdx.x;   // one 8-elem chunk
  const int bl = i8 >> 15;                         // / 32768
  const int r  = i8 & 32767;
  const int h  = r >> 8;
  const int t8 = r & 255;
  const int b  = b_base + bl;
  u16* p = Vt + ((size_t)b * H_ + h) * T_ + t8 * 8;
  const float* csp = colsum + (size_t)b * T_ + t8 * 8;
  short8 v = *(short8*)p;
  short8 o;
#pragma unroll
  for (int j = 0; j < 8; ++j) {
    float f = ubf16((u16)v[j]) / csp[j];
    o[j] = (short)bf16u(f);
  }
  *(short8*)p = o;
}

// ---------------- kernel 4: O += P @ V' (causal GEMM, k-split, atomic accumulate) ----
__global__ __launch_bounds__(256) void k_pv(const u16* __restrict__ P, const u16* __restrict__ Vt,
                                            float* __restrict__ out, int b_base) {
  __shared__ __align__(16) u16 Pt[128 * 128];
  __shared__ __align__(16) u16 Vs[128 * 128];
  const int id = blockIdx.x;
  const int bl = blockIdx.y;
  const int b  = b_base + bl;
  // decode (qt, chunk) with chunks(qt) = ceil((qt+1)/2)
  int qt = 0, cum = 0;
#pragma unroll
  for (int j = 0; j < 16; ++j) {
    const int n = (j + 2) >> 1;
    if (id < cum + n) { qt = j; break; }
    cum += n;
  }
  const int c   = id - cum;
  const int nch = (qt + 2) >> 1;
  const int kt0 = c * (qt + 1) / nch;
  const int kt1 = (c + 1) * (qt + 1) / nch;

  const int lane = threadIdx.x & 63, wid = threadIdx.x >> 6;
  const int ln = lane & 15, hi = lane >> 4;
  const int wq0 = wid * 32;

  f32x4 acc[2][8] = {};
  for (int kt = kt0; kt < kt1; ++kt) {
    const u16* ptile = P + (((size_t)bl * 136 + (size_t)qt * (qt + 1) / 2 + kt) << 14);
    stage_tile<128, 256, true>((const char*)ptile, 256, (char*)Pt);
    stage_tile<128, 256, true>((const char*)(Vt + (size_t)b * H_ * T_ + kt * 128), T_ * 2, (char*)Vs);
    __syncthreads();
#pragma unroll
    for (int kk = 0; kk < 4; ++kk) {
      short8 a[2], bf[8];
#pragma unroll
      for (int mf = 0; mf < 2; ++mf)
        a[mf] = fragr(Pt, wq0 + mf * 16 + ln, kk * 32 + hi * 8, 128);
#pragma unroll
      for (int nf = 0; nf < 8; ++nf)
        bf[nf] = fragr(Vs, nf * 16 + ln, kk * 32 + hi * 8, 128);
#pragma unroll
      for (int mf = 0; mf < 2; ++mf)
#pragma unroll
        for (int nf = 0; nf < 8; ++nf)
          acc[mf][nf] = MFMA_BF16(a[mf], bf[nf], acc[mf][nf]);
    }
    __syncthreads();
  }
#pragma unroll
  for (int mf = 0; mf < 2; ++mf)
#pragma unroll
    for (int nf = 0; nf < 8; ++nf)
#pragma unroll
      for (int i = 0; i < 4; ++i) {
        const int q = qt * 128 + wq0 + mf * 16 + hi * 4 + i;
        const int h = nf * 16 + ln;
        atomicAdd(&out[((size_t)b * T_ + q) * H_ + h], acc[mf][nf][i]);
      }
}

extern "C" void kernel_launch(void* const* d_in, const int* in_sizes, int n_in,
                              void* d_out, int out_size, void* d_ws, size_t ws_size,
                              hipStream_t stream) {
  const float* X  = (const float*)d_in[0];
  const float* Wq = (const float*)d_in[1];
  const float* Wk = (const float*)d_in[2];
  const float* Wv = (const float*)d_in[3];
  float* out = (float*)d_out;
  char* ws = (char*)d_ws;

  u16*  Xb     = (u16*)(ws + 0);              // 33,554,432 B (dead after qkv_gemm)
  u16*  Wt     = (u16*)(ws + 33554432);       //    786,432 B
  u16*  Qs     = (u16*)(ws + 34340864);       //  4,194,304 B
  u16*  Kb     = (u16*)(ws + 38535168);       //  4,194,304 B
  u16*  Vt     = (u16*)(ws + 42729472);       //  4,194,304 B
  float* colsum = (float*)(ws + 46923776);    //     65,536 B
  // P packed tiles: 136 tiles/batch * 32 KB.
  // Single-phase (8 batches, 34 MB) if ws allows; else two 4-batch phases with
  // P aliased over the dead Xb region (17.8 MB < 32 MB).
  int phases, nb;
  u16* Pb;
  if (ws_size >= 82640896ULL) { phases = 1; nb = 8; Pb = (u16*)(ws + 46989312); }
  else                        { phases = 2; nb = 4; Pb = (u16*)(ws + 0); }

  hipMemsetAsync(out, 0, (size_t)BT_ * H_ * sizeof(float), stream);
  hipMemsetAsync(colsum, 0, BT_ * sizeof(float), stream);
  k_convert_x<<<2048, 256, 0, stream>>>(X, Xb);
  k_build_wt<<<1536, 256, 0, stream>>>(Wq, Wk, Wv, Wt);
  k_qkv_gemm<<<dim3(128, 3), 256, 0, stream>>>(Xb, Wt, Qs, Kb, Vt);
  for (int p = 0; p < phases; ++p) {
    const int b_base = p * nb;
    k_score<<<dim3(136, nb), 256, 0, stream>>>(Qs, Kb, Pb, colsum, b_base);
    k_finalize_v<<<nb * 128, 256, 0, stream>>>(colsum, Vt, b_base);
    k_pv<<<dim3(72, nb), 256, 0, stream>>>(Pb, Vt, out, b_base);
  }
}

// Round 3
// 180.865 us; speedup vs baseline: 1.5454x; 1.1403x over previous
//
#include <hip/hip_runtime.h>
#include <hip/hip_bf16.h>
#include <stdint.h>

#define B_ 8
#define T_ 2048
#define E_ 1024
#define H_ 128
#define BT_ (B_*T_)

typedef unsigned short u16;
typedef unsigned int u32;
typedef __attribute__((ext_vector_type(4))) unsigned short u16x4;
typedef __attribute__((ext_vector_type(8))) short short8;
typedef __attribute__((ext_vector_type(4))) float f32x4;

#define MFMA_BF16(a,b,c) __builtin_amdgcn_mfma_f32_16x16x32_bf16((a),(b),(c),0,0,0)

__device__ __forceinline__ u16 bf16u(float f) {
  union { float f; unsigned u; } v; v.f = f;
  unsigned r = v.u + 0x7FFFu + ((v.u >> 16) & 1u);
  return (u16)(r >> 16);
}
__device__ __forceinline__ float ubf16(u16 u) {
  union { unsigned u; float f; } v; v.u = ((unsigned)u) << 16; return v.f;
}

// async global->LDS, 16B per lane; lds dest must be wave-uniform base.
__device__ __forceinline__ void gl16(const void* g, void* l) {
  __builtin_amdgcn_global_load_lds(
      (const __attribute__((address_space(1))) void*)g,
      (__attribute__((address_space(3))) void*)l, 16, 0, 0);
}

// Stage an R-row tile, CB bytes per row, into LDS laid out row-major [R][CB].
// SWZ: XOR-swizzle via pre-swizzled GLOBAL source (LDS dest stays linear).
// Readers XOR their 16B-slot index with (row&7). 4 waves assumed.
template<int R, int CB, bool SWZ>
__device__ __forceinline__ void stage_tile(const char* g, int gstride, char* lds) {
  const int lane = threadIdx.x & 63;
  const int wid  = threadIdx.x >> 6;
  constexpr int LPR   = CB / 16;
  constexpr int RPC   = 1024 / CB;
  constexpr int CALLS = (R * CB) / 1024;
  constexpr int CPW   = CALLS / 4;
#pragma unroll
  for (int c = 0; c < CPW; ++c) {
    const int call = wid * CPW + c;
    const int r0   = call * RPC;            // wave-uniform
    const int row  = r0 + lane / LPR;
    int s = lane % LPR;
    if (SWZ) s = s ^ (row & 7);
    gl16(g + (size_t)row * gstride + s * 16, lds + (size_t)r0 * CB);
  }
}

// Read a bf16x8 fragment from a SWZ-staged tile. colu16 multiple of 8.
__device__ __forceinline__ short8 fragr(const u16* lds, int row, int colu16, int CBu) {
  const int slot = (colu16 >> 3) ^ (row & 7);
  return *(const short8*)&lds[(size_t)row * CBu + (slot << 3)];
}

// ---------------- kernel 0: X fp32->bf16 + Wt build (fused) ----------------
__global__ void k_prep(const float* __restrict__ X, u16* __restrict__ Xb,
                       const float* __restrict__ Wq, const float* __restrict__ Wk,
                       const float* __restrict__ Wv, u16* __restrict__ Wt) {
  const int gidx = blockIdx.x * 256 + threadIdx.x;
  const int n4 = BT_ * E_ / 4;
  for (int i = gidx; i < n4; i += gridDim.x * 256) {
    float4 v = ((const float4*)X)[i];
    u16x4 o;
    o.x = bf16u(v.x); o.y = bf16u(v.y); o.z = bf16u(v.z); o.w = bf16u(v.w);
    ((u16x4*)Xb)[i] = o;
  }
  if (gidx < 384 * 1024) {
    int r = gidx >> 10;       // output row 0..383
    int e = gidx & 1023;      // col 0..1023
    int i = r >> 7;           // 0:q 1:k 2:v
    int h = r & 127;
    const float* W = (i == 0) ? Wq : (i == 1) ? Wk : Wv;
    float v = W[(size_t)e * 128 + h];
    if (i == 0) v *= 0.03125f;   // fold 1/sqrt(E)=1/32 into Q
    Wt[gidx] = bf16u(v);
  }
}

// ---------------- kernel 1: QKV GEMM (Bt input), 128x128 tile, BK=64, swizzled ----
__global__ __launch_bounds__(256) void k_qkv_gemm(const u16* __restrict__ Xb, const u16* __restrict__ Wt,
                                                  u16* __restrict__ Qs, u16* __restrict__ Kb,
                                                  u16* __restrict__ Vt) {
  __shared__ __align__(16) u16 As[128 * 64];
  __shared__ __align__(16) u16 Bs[128 * 64];
  const int m0   = blockIdx.x * 128;
  const int nsel = blockIdx.y;
  const int n0   = nsel * 128;
  const int lane = threadIdx.x & 63;
  const int wid  = threadIdx.x >> 6;
  const int ln = lane & 15, h4 = lane >> 4;
  const int wm = (wid >> 1) * 64, wn = (wid & 1) * 64;
  f32x4 acc[4][4] = {};
  for (int ks = 0; ks < E_; ks += 64) {
    stage_tile<128, 128, true>((const char*)(Xb + (size_t)m0 * E_ + ks), E_ * 2, (char*)As);
    stage_tile<128, 128, true>((const char*)(Wt + (size_t)n0 * E_ + ks), E_ * 2, (char*)Bs);
    __syncthreads();
#pragma unroll
    for (int kk = 0; kk < 2; ++kk) {
      short8 a[4], b[4];
#pragma unroll
      for (int mf = 0; mf < 4; ++mf)
        a[mf] = fragr(As, wm + mf * 16 + ln, kk * 32 + h4 * 8, 64);
#pragma unroll
      for (int nf = 0; nf < 4; ++nf)
        b[nf] = fragr(Bs, wn + nf * 16 + ln, kk * 32 + h4 * 8, 64);
#pragma unroll
      for (int mf = 0; mf < 4; ++mf)
#pragma unroll
        for (int nf = 0; nf < 4; ++nf)
          acc[mf][nf] = MFMA_BF16(a[mf], b[nf], acc[mf][nf]);
    }
    __syncthreads();
  }
#pragma unroll
  for (int mf = 0; mf < 4; ++mf)
#pragma unroll
    for (int nf = 0; nf < 4; ++nf)
#pragma unroll
      for (int i = 0; i < 4; ++i) {
        int r = m0 + wm + mf * 16 + h4 * 4 + i;
        int c = wn + nf * 16 + ln;
        u16 u = bf16u(acc[mf][nf][i]);
        if (nsel == 0)      Qs[(size_t)r * H_ + c] = u;
        else if (nsel == 1) Kb[(size_t)r * H_ + c] = u;
        else {
          int bb = r >> 11, t = r & (T_ - 1);
          Vt[((size_t)bb * H_ + c) * T_ + t] = u;   // V transposed per batch
        }
      }
}

// ---------------- kernel 2: score pass (snake-balanced) ----------------
// grid (chunk 8, pair 8, b 8). Pair a owns rows {a, 15-a}: 17 tiles, chunked
// into 8 pieces of 2-3. Per tile: S = Q K^T, exp+mask, colsum atomics,
// write exp(S) bf16 into packed global P tile (Ps assembled in K buffer).
__global__ __launch_bounds__(256) void k_score(const u16* __restrict__ Qs, const u16* __restrict__ Kb,
                                               u16* __restrict__ P, float* __restrict__ colsum) {
  __shared__ __align__(16) u16 Qb[128 * 128];   // 32KB
  __shared__ __align__(16) u16 Kf[128 * 128];   // 32KB (K, then Ps)
  const int c = blockIdx.x, a = blockIdx.y, b = blockIdx.z;
  const int lo = (c * 17) >> 3, hi = ((c + 1) * 17) >> 3;
  const int lane = threadIdx.x & 63, wid = threadIdx.x >> 6;
  const int ln = lane & 15, h4 = lane >> 4;
  const int wq0 = wid * 32;
  const bool evenlane = !(ln & 1);
  int curqt = -1;
  for (int t = lo; t < hi; ++t) {
    const int qt = (t <= a) ? a : 15 - a;
    const int kt = (t <= a) ? t : t - (a + 1);
    if (qt != curqt) {
      stage_tile<128, 256, true>((const char*)(Qs + ((size_t)b * T_ + qt * 128) * H_), H_ * 2, (char*)Qb);
      curqt = qt;
    }
    stage_tile<128, 256, true>((const char*)(Kb + ((size_t)b * T_ + kt * 128) * H_), H_ * 2, (char*)Kf);
    __syncthreads();   // staging done (vmcnt0)

    f32x4 acc[2][8] = {};
#pragma unroll
    for (int kk = 0; kk < 4; ++kk) {
      short8 av[2], bv[8];
#pragma unroll
      for (int mf = 0; mf < 2; ++mf)
        av[mf] = fragr(Qb, wq0 + mf * 16 + ln, kk * 32 + h4 * 8, 128);
#pragma unroll
      for (int nf = 0; nf < 8; ++nf)
        bv[nf] = fragr(Kf, nf * 16 + ln, kk * 32 + h4 * 8, 128);
#pragma unroll
      for (int mf = 0; mf < 2; ++mf)
#pragma unroll
        for (int nf = 0; nf < 8; ++nf)
          acc[mf][nf] = MFMA_BF16(av[mf], bv[nf], acc[mf][nf]);
    }

    const bool diag = (qt == kt);
#pragma unroll
    for (int nf = 0; nf < 8; ++nf) {
      float s = 0.f;
      const int k = nf * 16 + ln;
#pragma unroll
      for (int mf = 0; mf < 2; ++mf) {
#pragma unroll
        for (int i = 0; i < 4; ++i) {
          const int q = wq0 + mf * 16 + h4 * 4 + i;
          float w = __expf(acc[mf][nf][i]);
          if (diag && q < k) w = 0.f;
          acc[mf][nf][i] = w;
          s += w;
        }
      }
      s += __shfl_xor(s, 16);
      s += __shfl_xor(s, 32);
      if (h4 == 0) atomicAdd(&colsum[(size_t)b * T_ + kt * 128 + nf * 16 + ln], s);
    }
    __syncthreads();   // all K reads done

    // Ps (bf16, swizzled) into Kf
#pragma unroll
    for (int mf = 0; mf < 2; ++mf)
#pragma unroll
      for (int nf = 0; nf < 8; ++nf) {
        f32x4 v = acc[mf][nf];
        f32x4 pv;
#pragma unroll
        for (int i = 0; i < 4; ++i) pv[i] = __shfl_xor(v[i], 1);
#pragma unroll
        for (int j = 0; j < 2; ++j) {
          const int i = evenlane ? j : (2 + j);
          const float flo = evenlane ? v[i] : pv[i];
          const float fhh = evenlane ? pv[i] : v[i];
          const u32 pk = (u32)bf16u(flo) | ((u32)bf16u(fhh) << 16);
          const int row = wq0 + mf * 16 + h4 * 4 + i;
          const int kc  = nf * 16 + (ln & ~1);
          const int byt = row * 256 + ((((kc >> 3) ^ (row & 7)) << 4) | ((kc & 7) << 1));
          *(u32*)((char*)Kf + byt) = pk;
        }
      }
    __syncthreads();   // Ps complete

    u16* ptile = P + (((size_t)b * 136 + (size_t)qt * (qt + 1) / 2 + kt) << 14);
#pragma unroll
    for (int pass = 0; pass < 8; ++pass) {
      const int row = pass * 16 + (threadIdx.x >> 4);
      const int s   = threadIdx.x & 15;
      short8 val = *(const short8*)&Kf[row * 128 + ((s ^ (row & 7)) << 3)];
      *(short8*)&ptile[row * 128 + s * 8] = val;
    }
    __syncthreads();   // copy ds-reads done before next stage overwrites Kf
  }
}

// ---------------- kernel 3: V' = V * (1/colsum), in place on Vt ----------------
__global__ void k_finalize_v(const float* __restrict__ colsum, u16* __restrict__ Vt) {
  const int i8 = blockIdx.x * 256 + threadIdx.x;
  const int b  = i8 >> 15;
  const int r  = i8 & 32767;
  const int h  = r >> 8;
  const int t8 = r & 255;
  u16* p = Vt + ((size_t)b * H_ + h) * T_ + t8 * 8;
  const float* csp = colsum + (size_t)b * T_ + t8 * 8;
  short8 v = *(short8*)p;
  short8 o;
#pragma unroll
  for (int j = 0; j < 8; ++j) {
    float f = ubf16((u16)v[j]) / csp[j];
    o[j] = (short)bf16u(f);
  }
  *(short8*)p = o;
}

// ---------------- kernel 4: O = P @ V' (snake pairs, no atomics) ----------------
// grid 512: id = hq*64 + b*8 + a. Pair a owns qt={a,15-a}; hq = 16-col slice.
// Same-(b,a) wgs differ by 64 -> same XCD -> P tile L2-shared.
__global__ __launch_bounds__(256) void k_pv(const u16* __restrict__ P, const u16* __restrict__ Vt,
                                            float* __restrict__ out) {
  __shared__ __align__(16) u16 Pt[128 * 128];   // 32KB
  __shared__ __align__(16) u16 Vs[16 * 128];    // 4KB
  const int id = blockIdx.x;
  const int hq = id >> 6;
  const int b  = (id >> 3) & 7;
  const int a  = id & 7;
  const int lane = threadIdx.x & 63, wid = threadIdx.x >> 6;
  const int ln = lane & 15, h4 = lane >> 4;
  const int wq0 = wid * 32;
#pragma unroll
  for (int half = 0; half < 2; ++half) {
    const int qt = half ? (15 - a) : a;
    f32x4 acc[2] = {};
    for (int kt = 0; kt <= qt; ++kt) {
      const u16* ptile = P + (((size_t)b * 136 + (size_t)qt * (qt + 1) / 2 + kt) << 14);
      stage_tile<128, 256, true>((const char*)ptile, 256, (char*)Pt);
      stage_tile<16, 256, true>((const char*)(Vt + ((size_t)b * H_ + hq * 16) * T_ + kt * 128), T_ * 2, (char*)Vs);
      __syncthreads();
#pragma unroll
      for (int kk = 0; kk < 4; ++kk) {
        short8 bv = fragr(Vs, ln, kk * 32 + h4 * 8, 128);
#pragma unroll
        for (int mf = 0; mf < 2; ++mf) {
          short8 av = fragr(Pt, wq0 + mf * 16 + ln, kk * 32 + h4 * 8, 128);
          acc[mf] = MFMA_BF16(av, bv, acc[mf]);
        }
      }
      __syncthreads();
    }
#pragma unroll
    for (int mf = 0; mf < 2; ++mf)
#pragma unroll
      for (int i = 0; i < 4; ++i) {
        const int q = qt * 128 + wq0 + mf * 16 + h4 * 4 + i;
        out[((size_t)b * T_ + q) * H_ + hq * 16 + ln] = acc[mf][i];
      }
  }
}

extern "C" void kernel_launch(void* const* d_in, const int* in_sizes, int n_in,
                              void* d_out, int out_size, void* d_ws, size_t ws_size,
                              hipStream_t stream) {
  const float* X  = (const float*)d_in[0];
  const float* Wq = (const float*)d_in[1];
  const float* Wk = (const float*)d_in[2];
  const float* Wv = (const float*)d_in[3];
  float* out = (float*)d_out;
  char* ws = (char*)d_ws;

  u16 *Xb, *Wt, *Qs, *Kb, *Vt, *Pb;
  float* colsum;
  if (ws_size >= 82640896ULL) {
    // roomy layout
    Xb = (u16*)(ws + 0);                 // 33,554,432
    Wt = (u16*)(ws + 33554432);          //    786,432
    Qs = (u16*)(ws + 34340864);          //  4,194,304
    Kb = (u16*)(ws + 38535168);          //  4,194,304
    Vt = (u16*)(ws + 42729472);          //  4,194,304
    colsum = (float*)(ws + 46923776);    //     65,536
    Pb = (u16*)(ws + 46989312);          // 35,651,584 -> end 82,640,896
  } else {
    // tight layout: P aliases (dead) Xb+Wt region
    Qs = (u16*)(ws + 0);
    Kb = (u16*)(ws + 4194304);
    Vt = (u16*)(ws + 8388608);
    colsum = (float*)(ws + 12582912);
    Pb = (u16*)(ws + 12648448);          // 35,651,584 -> end 48,300,032
    Xb = (u16*)(ws + 12648448);          // inside P, dead before P written
    Wt = (u16*)(ws + 46202880);          // inside P, dead before P written
  }

  hipMemsetAsync(colsum, 0, BT_ * sizeof(float), stream);
  k_prep<<<2048, 256, 0, stream>>>(X, Xb, Wq, Wk, Wv, Wt);
  k_qkv_gemm<<<dim3(128, 3), 256, 0, stream>>>(Xb, Wt, Qs, Kb, Vt);
  k_score<<<dim3(8, 8, 8), 256, 0, stream>>>(Qs, Kb, Pb, colsum);
  k_finalize_v<<<1024, 256, 0, stream>>>(colsum, Vt);
  k_pv<<<512, 256, 0, stream>>>(Pb, Vt, out);
}

// Round 4
// 179.960 us; speedup vs baseline: 1.5531x; 1.0050x over previous
//
#include <hip/hip_runtime.h>
#include <hip/hip_bf16.h>
#include <stdint.h>

#define B_ 8
#define T_ 2048
#define E_ 1024
#define H_ 128
#define BT_ (B_*T_)

typedef unsigned short u16;
typedef unsigned int u32;
typedef __attribute__((ext_vector_type(4))) unsigned short u16x4;
typedef __attribute__((ext_vector_type(8))) short short8;
typedef __attribute__((ext_vector_type(4))) float f32x4;

#define MFMA_BF16(a,b,c) __builtin_amdgcn_mfma_f32_16x16x32_bf16((a),(b),(c),0,0,0)

#define SBAR() do { __builtin_amdgcn_sched_barrier(0); __builtin_amdgcn_s_barrier(); __builtin_amdgcn_sched_barrier(0); } while(0)
#define WAITL0() asm volatile("s_waitcnt lgkmcnt(0)" ::: "memory")

__device__ __forceinline__ u16 bf16u(float f) {
  union { float f; unsigned u; } v; v.f = f;
  unsigned r = v.u + 0x7FFFu + ((v.u >> 16) & 1u);
  return (u16)(r >> 16);
}
__device__ __forceinline__ float ubf16(u16 u) {
  union { unsigned u; float f; } v; v.u = ((unsigned)u) << 16; return v.f;
}

// async global->LDS, 16B per lane; lds dest must be wave-uniform base.
__device__ __forceinline__ void gl16(const void* g, void* l) {
  __builtin_amdgcn_global_load_lds(
      (const __attribute__((address_space(1))) void*)g,
      (__attribute__((address_space(3))) void*)l, 16, 0, 0);
}

// Stage an R-row tile, CB bytes per row, into LDS [R][CB] (linear dest).
// SWZ via pre-swizzled GLOBAL source; readers XOR 16B-slot with (row&7).
template<int R, int CB, bool SWZ>
__device__ __forceinline__ void stage_tile(const char* g, int gstride, char* lds) {
  const int lane = threadIdx.x & 63;
  const int wid  = threadIdx.x >> 6;
  constexpr int LPR   = CB / 16;
  constexpr int RPC   = 1024 / CB;
  constexpr int CALLS = (R * CB) / 1024;
  constexpr int CPW   = CALLS / 4;
#pragma unroll
  for (int c = 0; c < CPW; ++c) {
    const int call = wid * CPW + c;
    const int r0   = call * RPC;            // wave-uniform
    const int row  = r0 + lane / LPR;
    int s = lane % LPR;
    if (SWZ) s = s ^ (row & 7);
    gl16(g + (size_t)row * gstride + s * 16, lds + (size_t)r0 * CB);
  }
}

// Read a bf16x8 fragment from a SWZ-staged tile. colu16 multiple of 8.
__device__ __forceinline__ short8 fragr(const u16* lds, int row, int colu16, int CBu) {
  const int slot = (colu16 >> 3) ^ (row & 7);
  return *(const short8*)&lds[(size_t)row * CBu + (slot << 3)];
}

// ---------------- kernel 0: X fp32->bf16 + Wt build + colsum zero ----------------
__global__ void k_prep(const float* __restrict__ X, u16* __restrict__ Xb,
                       const float* __restrict__ Wq, const float* __restrict__ Wk,
                       const float* __restrict__ Wv, u16* __restrict__ Wt,
                       float* __restrict__ colsum) {
  const int gidx = blockIdx.x * 256 + threadIdx.x;
  const int n4 = BT_ * E_ / 4;
  for (int i = gidx; i < n4; i += gridDim.x * 256) {
    float4 v = ((const float4*)X)[i];
    u16x4 o;
    o.x = bf16u(v.x); o.y = bf16u(v.y); o.z = bf16u(v.z); o.w = bf16u(v.w);
    ((u16x4*)Xb)[i] = o;
  }
  if (gidx < BT_) colsum[gidx] = 0.f;
  if (gidx < 384 * 1024) {
    int r = gidx >> 10;
    int e = gidx & 1023;
    int i = r >> 7;           // 0:q 1:k 2:v
    int h = r & 127;
    const float* W = (i == 0) ? Wq : (i == 1) ? Wk : Wv;
    float v = W[(size_t)e * 128 + h];
    if (i == 0) v *= 0.03125f;   // fold 1/sqrt(E)=1/32 into Q
    Wt[gidx] = bf16u(v);
  }
}

// ---------------- kernel 1: QKV GEMM, 128x128 tile, BK=64, dbuf + counted vmcnt ----
__global__ __launch_bounds__(256) void k_qkv_gemm(const u16* __restrict__ Xb, const u16* __restrict__ Wt,
                                                  u16* __restrict__ Qs, u16* __restrict__ Kb,
                                                  u16* __restrict__ Vt) {
  __shared__ __align__(16) u16 As[2][128 * 64];
  __shared__ __align__(16) u16 Bs[2][128 * 64];
  const int m0   = blockIdx.x * 128;
  const int nsel = blockIdx.y;
  const int n0   = nsel * 128;
  const int lane = threadIdx.x & 63;
  const int wid  = threadIdx.x >> 6;
  const int ln = lane & 15, h4 = lane >> 4;
  const int wm = (wid >> 1) * 64, wn = (wid & 1) * 64;
  f32x4 acc[4][4] = {};

  auto stage = [&](int t, int buf) {
    stage_tile<128, 128, true>((const char*)(Xb + (size_t)m0 * E_ + t * 64), E_ * 2, (char*)As[buf]);
    stage_tile<128, 128, true>((const char*)(Wt + (size_t)n0 * E_ + t * 64), E_ * 2, (char*)Bs[buf]);
  };
  stage(0, 0);
  for (int t = 0; t < 16; ++t) {
    const int cur = t & 1;
    if (t < 15) stage(t + 1, cur ^ 1);
    if (t < 15) asm volatile("s_waitcnt vmcnt(8)" ::: "memory");
    else        asm volatile("s_waitcnt vmcnt(0)" ::: "memory");
    SBAR();
#pragma unroll
    for (int kk = 0; kk < 2; ++kk) {
      short8 a[4], b[4];
#pragma unroll
      for (int mf = 0; mf < 4; ++mf)
        a[mf] = fragr(As[cur], wm + mf * 16 + ln, kk * 32 + h4 * 8, 64);
#pragma unroll
      for (int nf = 0; nf < 4; ++nf)
        b[nf] = fragr(Bs[cur], wn + nf * 16 + ln, kk * 32 + h4 * 8, 64);
#pragma unroll
      for (int mf = 0; mf < 4; ++mf)
#pragma unroll
        for (int nf = 0; nf < 4; ++nf)
          acc[mf][nf] = MFMA_BF16(a[mf], b[nf], acc[mf][nf]);
    }
    WAITL0();
    SBAR();
  }
#pragma unroll
  for (int mf = 0; mf < 4; ++mf)
#pragma unroll
    for (int nf = 0; nf < 4; ++nf)
#pragma unroll
      for (int i = 0; i < 4; ++i) {
        int r = m0 + wm + mf * 16 + h4 * 4 + i;
        int c = wn + nf * 16 + ln;
        u16 u = bf16u(acc[mf][nf][i]);
        if (nsel == 0)      Qs[(size_t)r * H_ + c] = u;
        else if (nsel == 1) Kb[(size_t)r * H_ + c] = u;
        else {
          int bb = r >> 11, tt = r & (T_ - 1);
          Vt[((size_t)bb * H_ + c) * T_ + tt] = u;   // V transposed per batch
        }
      }
}

// ---------------- kernel 2: score pass (snake-balanced, Q in regs, direct P store) ---
// grid (chunk 8, pair 8, b 8). Pair a owns rows {a, 15-a}: 17 tiles in 8 chunks.
__global__ __launch_bounds__(256) void k_score(const u16* __restrict__ Qs, const u16* __restrict__ Kb,
                                               u16* __restrict__ P, float* __restrict__ colsum) {
  __shared__ __align__(16) u16 Kf[128 * 128];   // 32KB
  const int c = blockIdx.x, a = blockIdx.y, b = blockIdx.z;
  const int lo = (c * 17) >> 3, hi = ((c + 1) * 17) >> 3;
  const int lane = threadIdx.x & 63, wid = threadIdx.x >> 6;
  const int ln = lane & 15, h4 = lane >> 4;
  const int wq0 = wid * 32;
  const bool evenlane = !(ln & 1);
  int curqt = -1;
  short8 qa[2][4];   // [mf][kk] Q fragments held in registers across the row-run
  for (int t = lo; t < hi; ++t) {
    const int qt = (t <= a) ? a : 15 - a;
    const int kt = (t <= a) ? t : t - (a + 1);
    stage_tile<128, 256, true>((const char*)(Kb + ((size_t)b * T_ + kt * 128) * H_), H_ * 2, (char*)Kf);
    if (qt != curqt) {
#pragma unroll
      for (int mf = 0; mf < 2; ++mf)
#pragma unroll
        for (int kk = 0; kk < 4; ++kk)
          qa[mf][kk] = *(const short8*)&Qs[((size_t)b * T_ + qt * 128 + wq0 + mf * 16 + ln) * H_ + kk * 32 + h4 * 8];
      curqt = qt;
    }
    asm volatile("s_waitcnt vmcnt(0)" ::: "memory");
    SBAR();

    f32x4 acc[2][8] = {};
#pragma unroll
    for (int kk = 0; kk < 4; ++kk) {
#pragma unroll
      for (int nf = 0; nf < 8; ++nf) {
        short8 bv = fragr(Kf, nf * 16 + ln, kk * 32 + h4 * 8, 128);
#pragma unroll
        for (int mf = 0; mf < 2; ++mf)
          acc[mf][nf] = MFMA_BF16(qa[mf][kk], bv, acc[mf][nf]);
      }
    }

    const bool diag = (qt == kt);
#pragma unroll
    for (int nf = 0; nf < 8; ++nf) {
      float s = 0.f;
      const int k = nf * 16 + ln;
#pragma unroll
      for (int mf = 0; mf < 2; ++mf) {
#pragma unroll
        for (int i = 0; i < 4; ++i) {
          const int q = wq0 + mf * 16 + h4 * 4 + i;
          float w = __expf(acc[mf][nf][i]);
          if (diag && q < k) w = 0.f;
          acc[mf][nf][i] = w;
          s += w;
        }
      }
      s += __shfl_xor(s, 16);
      s += __shfl_xor(s, 32);
      if (h4 == 0) atomicAdd(&colsum[(size_t)b * T_ + kt * 128 + nf * 16 + ln], s);
    }

    // direct global P store (linear tile layout), u32 paired across lanes
    u16* ptile = P + (((size_t)b * 136 + (size_t)qt * (qt + 1) / 2 + kt) << 14);
#pragma unroll
    for (int mf = 0; mf < 2; ++mf)
#pragma unroll
      for (int nf = 0; nf < 8; ++nf) {
        f32x4 v = acc[mf][nf];
        f32x4 pv_;
#pragma unroll
        for (int i = 0; i < 4; ++i) pv_[i] = __shfl_xor(v[i], 1);
#pragma unroll
        for (int j = 0; j < 2; ++j) {
          const int i = evenlane ? j : (2 + j);
          const float flo = evenlane ? v[i] : pv_[i];
          const float fhh = evenlane ? pv_[i] : v[i];
          const u32 pk = (u32)bf16u(flo) | ((u32)bf16u(fhh) << 16);
          const int row = wq0 + mf * 16 + h4 * 4 + i;
          const int kc  = nf * 16 + (ln & ~1);
          *(u32*)((char*)ptile + row * 256 + kc * 2) = pk;
        }
      }
    WAITL0();   // Kf ds_reads retired; P stores NOT drained
    SBAR();
  }
}

// ---------------- kernel 3: V' = V * (1/colsum), in place on Vt ----------------
__global__ void k_finalize_v(const float* __restrict__ colsum, u16* __restrict__ Vt) {
  const int i8 = blockIdx.x * 256 + threadIdx.x;
  const int b  = i8 >> 15;
  const int r  = i8 & 32767;
  const int h  = r >> 8;
  const int t8 = r & 255;
  u16* p = Vt + ((size_t)b * H_ + h) * T_ + t8 * 8;
  const float* csp = colsum + (size_t)b * T_ + t8 * 8;
  short8 v = *(short8*)p;
  short8 o;
#pragma unroll
  for (int j = 0; j < 8; ++j) {
    float f = ubf16((u16)v[j]) / csp[j];
    o[j] = (short)bf16u(f);
  }
  *(short8*)p = o;
}

// ---------------- kernel 4: O = P @ V' (snake pairs, dbuf + counted vmcnt) ----------
// grid 512: id = hq*64 + b*8 + a. Pair a owns qt={a,15-a} -> 17 flat tiles.
__global__ __launch_bounds__(256) void k_pv(const u16* __restrict__ P, const u16* __restrict__ Vt,
                                            float* __restrict__ out) {
  __shared__ __align__(16) u16 Pt[2][128 * 128];   // 64KB
  __shared__ __align__(16) u16 Vs[2][16 * 128];    // 8KB
  const int id = blockIdx.x;
  const int hq = id >> 6;
  const int b  = (id >> 3) & 7;
  const int a  = id & 7;
  const int lane = threadIdx.x & 63, wid = threadIdx.x >> 6;
  const int ln = lane & 15, h4 = lane >> 4;
  const int wq0 = wid * 32;

  auto stage = [&](int t, int buf) {
    const int qt = (t <= a) ? a : 15 - a;
    const int kt = (t <= a) ? t : t - (a + 1);
    const u16* ptile = P + (((size_t)b * 136 + (size_t)qt * (qt + 1) / 2 + kt) << 14);
    stage_tile<128, 256, true>((const char*)ptile, 256, (char*)Pt[buf]);
    stage_tile<16, 256, true>((const char*)(Vt + ((size_t)b * H_ + hq * 16) * T_ + kt * 128), T_ * 2, (char*)Vs[buf]);
  };

  stage(0, 0);
  f32x4 acc[2] = {};
  for (int t = 0; t < 17; ++t) {
    const int cur = t & 1;
    if (t < 16) stage(t + 1, cur ^ 1);
    if (t < 16) asm volatile("s_waitcnt vmcnt(9)" ::: "memory");
    else        asm volatile("s_waitcnt vmcnt(0)" ::: "memory");
    SBAR();
#pragma unroll
    for (int kk = 0; kk < 4; ++kk) {
      short8 bv = fragr(Vs[cur], ln, kk * 32 + h4 * 8, 128);
#pragma unroll
      for (int mf = 0; mf < 2; ++mf) {
        short8 av = fragr(Pt[cur], wq0 + mf * 16 + ln, kk * 32 + h4 * 8, 128);
        acc[mf] = MFMA_BF16(av, bv, acc[mf]);
      }
    }
    if (t == a || t == 16) {
      const int qt = (t == a) ? a : 15 - a;
#pragma unroll
      for (int mf = 0; mf < 2; ++mf) {
#pragma unroll
        for (int i = 0; i < 4; ++i) {
          const int q = qt * 128 + wq0 + mf * 16 + h4 * 4 + i;
          out[((size_t)b * T_ + q) * H_ + hq * 16 + ln] = acc[mf][i];
        }
        acc[mf] = (f32x4){0.f, 0.f, 0.f, 0.f};
      }
    }
    WAITL0();
    SBAR();
  }
}

extern "C" void kernel_launch(void* const* d_in, const int* in_sizes, int n_in,
                              void* d_out, int out_size, void* d_ws, size_t ws_size,
                              hipStream_t stream) {
  const float* X  = (const float*)d_in[0];
  const float* Wq = (const float*)d_in[1];
  const float* Wk = (const float*)d_in[2];
  const float* Wv = (const float*)d_in[3];
  float* out = (float*)d_out;
  char* ws = (char*)d_ws;

  u16 *Xb, *Wt, *Qs, *Kb, *Vt, *Pb;
  float* colsum;
  if (ws_size >= 82640896ULL) {
    Xb = (u16*)(ws + 0);                 // 33,554,432
    Wt = (u16*)(ws + 33554432);          //    786,432
    Qs = (u16*)(ws + 34340864);          //  4,194,304
    Kb = (u16*)(ws + 38535168);          //  4,194,304
    Vt = (u16*)(ws + 42729472);          //  4,194,304
    colsum = (float*)(ws + 46923776);    //     65,536
    Pb = (u16*)(ws + 46989312);          // 35,651,584 -> end 82,640,896
  } else {
    Qs = (u16*)(ws + 0);
    Kb = (u16*)(ws + 4194304);
    Vt = (u16*)(ws + 8388608);
    colsum = (float*)(ws + 12582912);
    Pb = (u16*)(ws + 12648448);          // 35,651,584 -> end 48,300,032
    Xb = (u16*)(ws + 12648448);          // inside P, dead before P written
    Wt = (u16*)(ws + 46202880);          // inside P, dead before P written
  }

  k_prep<<<2048, 256, 0, stream>>>(X, Xb, Wq, Wk, Wv, Wt, colsum);
  k_qkv_gemm<<<dim3(128, 3), 256, 0, stream>>>(Xb, Wt, Qs, Kb, Vt);
  k_score<<<dim3(8, 8, 8), 256, 0, stream>>>(Qs, Kb, Pb, colsum);
  k_finalize_v<<<1024, 256, 0, stream>>>(colsum, Vt);
  k_pv<<<512, 256, 0, stream>>>(Pb, Vt, out);
}